// Round 6
// baseline (335.098 us; speedup 1.0000x reference)
//
#include <hip/hip_runtime.h>
#include <hip/hip_bf16.h>

#define SLEN 2048
#define DH   64
#define KT   64
#define NTL  32
#define NBH  64

typedef __attribute__((ext_vector_type(8))) short bf16x8;
typedef __attribute__((ext_vector_type(4))) float f32x4;

__device__ __forceinline__ short f2bf_hw(float f) {
    union { __hip_bfloat16 b; short s; } u;
    u.b = __float2bfloat16(f);            // HW RNE convert
    return u.s;
}
__device__ __forceinline__ short2 f2bf2_hw(float a, float b) {
    union { __hip_bfloat162 b2; short2 s2; } u;
    u.b2 = __float22bfloat162_rn(float2{a, b});   // v_cvt_pk_bf16_f32
    return u.s2;
}

// legacy bit-op convert (fallback kernel only — proven path, leave untouched)
__device__ __forceinline__ short f2bf(float f) {
    union { float f; unsigned u; } v; v.f = f;
    unsigned u = v.u;
    u += 0x7fff + ((u >> 16) & 1);
    return (short)(u >> 16);
}

// ---- one-time convert: K -> bf16 row-major; V -> bf16 transposed [d][s] ----
__global__ __launch_bounds__(256)
void conv_kernel(const float* __restrict__ K, const float* __restrict__ V,
                 short* __restrict__ Kw, short* __restrict__ Vt)
{
    __shared__ short lvt[DH][72];
    const int tid = threadIdx.x;
    const int blk = (int)blockIdx.x;
    const int bh = blk >> 5, t = blk & 31;
    const int r = tid >> 2;            // row in 64-tile
    const int c = (tid & 3) << 4;      // col group (16 elems)

    if (blockIdx.y == 1) {             // V: transpose via LDS
        const float4* src = (const float4*)(V + ((size_t)bh * SLEN + t * KT + r) * DH + c);
        #pragma unroll
        for (int q4 = 0; q4 < 4; ++q4) {
            float4 fv = src[q4];
            short2 p0 = f2bf2_hw(fv.x, fv.y);
            short2 p1 = f2bf2_hw(fv.z, fv.w);
            lvt[c + q4*4 + 0][r] = p0.x;
            lvt[c + q4*4 + 1][r] = p0.y;
            lvt[c + q4*4 + 2][r] = p1.x;
            lvt[c + q4*4 + 3][r] = p1.y;
        }
        __syncthreads();
        short* dst = Vt + (size_t)bh * DH * SLEN + (size_t)r * SLEN + t * KT + c;
        *(bf16x8*)dst       = *(const bf16x8*)&lvt[r][c];
        *(bf16x8*)(dst + 8) = *(const bf16x8*)&lvt[r][c + 8];
    } else {                           // K: straight convert
        size_t off = ((size_t)bh * SLEN + t * KT + r) * DH + c;
        const float4* src = (const float4*)(K + off);
        alignas(16) short tmp[16];
        #pragma unroll
        for (int q4 = 0; q4 < 4; ++q4) {
            float4 fv = src[q4];
            *(short2*)&tmp[q4*4]     = f2bf2_hw(fv.x, fv.y);
            *(short2*)&tmp[q4*4 + 2] = f2bf2_hw(fv.z, fv.w);
        }
        *(bf16x8*)(Kw + off)     = *(const bf16x8*)&tmp[0];
        *(bf16x8*)(Kw + off + 8) = *(const bf16x8*)&tmp[8];
    }
}

// ---- main: R5 skeleton; pass 2 split by K-half (block = bh,qt,kh) ----
__global__ __launch_bounds__(256, 3)
void sdpa_main(const float* __restrict__ Q, const short* __restrict__ Kw,
               const short* __restrict__ Vt, float* __restrict__ out,
               float* __restrict__ attn)
{
    __shared__ __align__(16) short lk[2][KT][72];
    __shared__ __align__(16) short lv[2][DH][72];
    __shared__ __align__(16) short lp[4][16][72];

    const int tid = threadIdx.x;
    const int w = tid >> 6, lane = tid & 63, g = lane >> 4, lc = lane & 15;

    const int bid = (int)blockIdx.x;               // T1 XCD swizzle (4096 % 8 == 0)
    const int wg = (bid & 7) * 512 + (bid >> 3);
    const int kh = wg & 1, qt = (wg >> 1) & 31, bh = wg >> 6;

    const short* Ktile = Kw + (size_t)bh * SLEN * DH;
    const short* Vbh   = Vt + (size_t)bh * DH * SLEN;
    float* outb  = out  + ((size_t)bh * SLEN + qt * KT) * DH;
    float* attnb = attn + ((size_t)bh * SLEN + qt * KT) * SLEN;

    // staging decomposition: 16B chunk i -> row i>>3, col (i&7)*8
    const int srow = tid >> 3;        // 0..31
    const int scol = (tid & 7) * 8;   // 0..56

    // Q fragments direct from fp32 global, 0.125 scale folded (exact pow2)
    bf16x8 qf[2];
    {
        const float* qsrc = Q + ((size_t)bh * SLEN + qt * KT + w * 16 + lc) * DH + g * 8;
        #pragma unroll
        for (int s = 0; s < 2; ++s)
            #pragma unroll
            for (int j = 0; j < 4; ++j) {
                short2 p = f2bf2_hw(qsrc[s * 32 + 2 * j] * 0.125f,
                                    qsrc[s * 32 + 2 * j + 1] * 0.125f);
                qf[s][2 * j]     = p.x;
                qf[s][2 * j + 1] = p.y;
            }
    }

    // ===== pass 1: per-lane sum-exp over FULL K (both halves need full row sum) =====
    float lsum[4] = {0.f, 0.f, 0.f, 0.f};
    {   // prologue: stage K tile 0
        const short* ks = Ktile;
        bf16x8 k0 = *(const bf16x8*)(ks + tid * 8);
        bf16x8 k1 = *(const bf16x8*)(ks + (tid + 256) * 8);
        *(bf16x8*)&lk[0][srow][scol]      = k0;
        *(bf16x8*)&lk[0][srow + 32][scol] = k1;
    }
    __syncthreads();

    for (int t = 0; t < NTL; ++t) {
        bf16x8 k0, k1;
        const bool pre = (t + 1 < NTL);
        if (pre) {
            const short* ks = Ktile + (t + 1) * (KT * DH);
            k0 = *(const bf16x8*)(ks + tid * 8);
            k1 = *(const bf16x8*)(ks + (tid + 256) * 8);
        }

        f32x4 acc[4];
        #pragma unroll
        for (int nt = 0; nt < 4; ++nt) acc[nt] = (f32x4){0.f,0.f,0.f,0.f};
        #pragma unroll
        for (int s = 0; s < 2; ++s)
            #pragma unroll
            for (int nt = 0; nt < 4; ++nt) {
                bf16x8 kf = *(const bf16x8*)&lk[t & 1][nt * 16 + lc][s * 32 + g * 8];
                acc[nt] = __builtin_amdgcn_mfma_f32_16x16x32_bf16(qf[s], kf, acc[nt], 0, 0, 0);
            }
        #pragma unroll
        for (int nt = 0; nt < 4; ++nt)
            #pragma unroll
            for (int e = 0; e < 4; ++e)
                lsum[e] += __expf(acc[nt][e]);

        if (pre) {
            *(bf16x8*)&lk[(t + 1) & 1][srow][scol]      = k0;
            *(bf16x8*)&lk[(t + 1) & 1][srow + 32][scol] = k1;
        }
        __syncthreads();
    }

    float c2[4];
    #pragma unroll
    for (int e = 0; e < 4; ++e) {
        float s = lsum[e];
        s += __shfl_xor(s, 1); s += __shfl_xor(s, 2);
        s += __shfl_xor(s, 4); s += __shfl_xor(s, 8);
        c2[e] = -__logf(s);    // p = exp(s + ln(1/l))
    }

    // ===== pass 2: K-half [kh*16, kh*16+16): recompute S, write attn, partial PV =====
    f32x4 oacc[4];
    #pragma unroll
    for (int nt = 0; nt < 4; ++nt) oacc[nt] = (f32x4){0.f,0.f,0.f,0.f};

    const int t0 = kh * 16, t1 = t0 + 16;

    {   // prologue: stage K + V tile t0
        const short* ks = Ktile + t0 * (KT * DH);
        const short* vs = Vbh + t0 * KT;
        bf16x8 k0 = *(const bf16x8*)(ks + tid * 8);
        bf16x8 k1 = *(const bf16x8*)(ks + (tid + 256) * 8);
        bf16x8 v0 = *(const bf16x8*)(vs + (size_t)srow * SLEN + scol);
        bf16x8 v1 = *(const bf16x8*)(vs + (size_t)(srow + 32) * SLEN + scol);
        *(bf16x8*)&lk[t0 & 1][srow][scol]      = k0;
        *(bf16x8*)&lk[t0 & 1][srow + 32][scol] = k1;
        *(bf16x8*)&lv[t0 & 1][srow][scol]      = v0;
        *(bf16x8*)&lv[t0 & 1][srow + 32][scol] = v1;
    }
    __syncthreads();

    for (int t = t0; t < t1; ++t) {
        bf16x8 k0, k1, v0, v1;
        const bool pre = (t + 1 < t1);
        if (pre) {
            const short* ks = Ktile + (t + 1) * (KT * DH);
            const short* vs = Vbh + (t + 1) * KT;
            k0 = *(const bf16x8*)(ks + tid * 8);
            k1 = *(const bf16x8*)(ks + (tid + 256) * 8);
            v0 = *(const bf16x8*)(vs + (size_t)srow * SLEN + scol);
            v1 = *(const bf16x8*)(vs + (size_t)(srow + 32) * SLEN + scol);
        }

        f32x4 acc[4];
        #pragma unroll
        for (int nt = 0; nt < 4; ++nt) acc[nt] = (f32x4){0.f,0.f,0.f,0.f};
        #pragma unroll
        for (int s = 0; s < 2; ++s)
            #pragma unroll
            for (int nt = 0; nt < 4; ++nt) {
                bf16x8 kf = *(const bf16x8*)&lk[t & 1][nt * 16 + lc][s * 32 + g * 8];
                acc[nt] = __builtin_amdgcn_mfma_f32_16x16x32_bf16(qf[s], kf, acc[nt], 0, 0, 0);
            }

        // P = exp(s + ln(1/l)) : nontemporal fp32 attn store + HW-cvt bf16 into LDS
        #pragma unroll
        for (int nt = 0; nt < 4; ++nt)
            #pragma unroll
            for (int e = 0; e < 4; ++e) {
                float p = __expf(acc[nt][e] + c2[e]);
                __builtin_nontemporal_store(
                    p, &attnb[(size_t)(w * 16 + 4 * g + e) * SLEN + t * KT + nt * 16 + lc]);
                lp[w][4 * g + e][nt * 16 + lc] = f2bf_hw(p);
            }

        // PV from V^T tile in LDS
        #pragma unroll
        for (int kc = 0; kc < 2; ++kc) {
            bf16x8 pf = *(const bf16x8*)&lp[w][lc][kc * 32 + g * 8];
            #pragma unroll
            for (int nt = 0; nt < 4; ++nt) {
                bf16x8 vf = *(const bf16x8*)&lv[t & 1][nt * 16 + lc][kc * 32 + g * 8];
                oacc[nt] = __builtin_amdgcn_mfma_f32_16x16x32_bf16(pf, vf, oacc[nt], 0, 0, 0);
            }
        }

        if (pre) {
            *(bf16x8*)&lk[(t + 1) & 1][srow][scol]      = k0;
            *(bf16x8*)&lk[(t + 1) & 1][srow + 32][scol] = k1;
            *(bf16x8*)&lv[(t + 1) & 1][srow][scol]      = v0;
            *(bf16x8*)&lv[(t + 1) & 1][srow + 32][scol] = v1;
        }
        __syncthreads();
    }

    // partial-PV combine: exactly 2 commutative HW f32 atomic adds per element
    // onto a zeroed buffer -> bitwise deterministic
    #pragma unroll
    for (int nt = 0; nt < 4; ++nt)
        #pragma unroll
        for (int e = 0; e < 4; ++e)
            unsafeAtomicAdd(&outb[(w * 16 + 4 * g + e) * DH + nt * 16 + lc], oacc[nt][e]);
}

// ---- fallback (R2 kernel verbatim, used only if d_ws is too small) ----
__global__ __launch_bounds__(256, 3)
void sdpa_fallback(const float* __restrict__ Q, const float* __restrict__ K,
                   const float* __restrict__ V, float* __restrict__ out,
                   float* __restrict__ attn)
{
    __shared__ __align__(16) short lk[2][KT][72];
    __shared__ __align__(16) short lv[2][DH * 72];
    __shared__ __align__(16) short lp[4][16][72];

    const int tid = threadIdx.x;
    const int w = tid >> 6, lane = tid & 63, g = lane >> 4, lc = lane & 15;
    const int bid = (int)blockIdx.x;
    const int wg = (bid & 7) * 256 + (bid >> 3);
    const int qt = wg & 31, bh = wg >> 5;

    const float*  Qb  = Q + ((size_t)bh * SLEN + qt * 64) * DH;
    const float4* Kb4 = (const float4*)(K + (size_t)bh * SLEN * DH);
    const float4* Vb4 = (const float4*)(V + (size_t)bh * SLEN * DH);
    float* outb  = out  + ((size_t)bh * SLEN + qt * 64) * DH;
    float* attnb = attn + ((size_t)bh * SLEN + qt * 64) * SLEN;

    const int sr = (tid >> 4);
    const int sc = (tid & 15) * 4;

    bf16x8 qf[2];
    {
        const float* qsrc = Qb + (w * 16 + lc) * DH + g * 8;
        #pragma unroll
        for (int s = 0; s < 2; ++s)
            #pragma unroll
            for (int j = 0; j < 8; ++j)
                qf[s][j] = f2bf(qsrc[s * 32 + j] * 0.125f);
    }

    float lsum[4] = {0.f, 0.f, 0.f, 0.f};
    {
        float4 kr[4];
        #pragma unroll
        for (int q4 = 0; q4 < 4; ++q4) kr[q4] = Kb4[q4 * 256 + tid];
        #pragma unroll
        for (int q4 = 0; q4 < 4; ++q4) {
            short4 s4 = { f2bf(kr[q4].x), f2bf(kr[q4].y), f2bf(kr[q4].z), f2bf(kr[q4].w) };
            *(short4*)&lk[0][q4 * 16 + sr][sc] = s4;
        }
    }
    __syncthreads();
    for (int t = 0; t < NTL; ++t) {
        float4 kr[4];
        const bool pre = (t + 1 < NTL);
        if (pre) {
            const float4* src = Kb4 + (size_t)(t + 1) * 1024;
            #pragma unroll
            for (int q4 = 0; q4 < 4; ++q4) kr[q4] = src[q4 * 256 + tid];
        }
        f32x4 acc[4];
        #pragma unroll
        for (int nt = 0; nt < 4; ++nt) acc[nt] = (f32x4){0.f,0.f,0.f,0.f};
        #pragma unroll
        for (int s = 0; s < 2; ++s)
            #pragma unroll
            for (int nt = 0; nt < 4; ++nt) {
                bf16x8 kf = *(const bf16x8*)&lk[t & 1][nt * 16 + lc][s * 32 + g * 8];
                acc[nt] = __builtin_amdgcn_mfma_f32_16x16x32_bf16(qf[s], kf, acc[nt], 0, 0, 0);
            }
        #pragma unroll
        for (int nt = 0; nt < 4; ++nt)
            #pragma unroll
            for (int e = 0; e < 4; ++e)
                lsum[e] += __expf(acc[nt][e]);
        if (pre) {
            #pragma unroll
            for (int q4 = 0; q4 < 4; ++q4) {
                short4 s4 = { f2bf(kr[q4].x), f2bf(kr[q4].y), f2bf(kr[q4].z), f2bf(kr[q4].w) };
                *(short4*)&lk[(t + 1) & 1][q4 * 16 + sr][sc] = s4;
            }
        }
        __syncthreads();
    }
    float c2[4];
    #pragma unroll
    for (int e = 0; e < 4; ++e) {
        float s = lsum[e];
        s += __shfl_xor(s, 1); s += __shfl_xor(s, 2);
        s += __shfl_xor(s, 4); s += __shfl_xor(s, 8);
        c2[e] = -__logf(s);
    }
    f32x4 oacc[4];
    #pragma unroll
    for (int nt = 0; nt < 4; ++nt) oacc[nt] = (f32x4){0.f,0.f,0.f,0.f};
    {
        float4 kr[4], vr[4];
        #pragma unroll
        for (int q4 = 0; q4 < 4; ++q4) { kr[q4] = Kb4[q4 * 256 + tid]; vr[q4] = Vb4[q4 * 256 + tid]; }
        #pragma unroll
        for (int q4 = 0; q4 < 4; ++q4) {
            short4 s4 = { f2bf(kr[q4].x), f2bf(kr[q4].y), f2bf(kr[q4].z), f2bf(kr[q4].w) };
            *(short4*)&lk[0][q4 * 16 + sr][sc] = s4;
            float fv[4] = { vr[q4].x, vr[q4].y, vr[q4].z, vr[q4].w };
            #pragma unroll
            for (int j = 0; j < 4; ++j) {
                int d = sc + j;
                int idx = (d * 72 + q4 * 16 + sr) ^ (((d >> 3) & 7) << 3);
                lv[0][idx] = f2bf(fv[j]);
            }
        }
    }
    __syncthreads();
    for (int t = 0; t < NTL; ++t) {
        float4 kr[4], vr[4];
        const bool pre = (t + 1 < NTL);
        if (pre) {
            const float4* ks = Kb4 + (size_t)(t + 1) * 1024;
            const float4* vs = Vb4 + (size_t)(t + 1) * 1024;
            #pragma unroll
            for (int q4 = 0; q4 < 4; ++q4) { kr[q4] = ks[q4 * 256 + tid]; vr[q4] = vs[q4 * 256 + tid]; }
        }
        f32x4 acc[4];
        #pragma unroll
        for (int nt = 0; nt < 4; ++nt) acc[nt] = (f32x4){0.f,0.f,0.f,0.f};
        #pragma unroll
        for (int s = 0; s < 2; ++s)
            #pragma unroll
            for (int nt = 0; nt < 4; ++nt) {
                bf16x8 kf = *(const bf16x8*)&lk[t & 1][nt * 16 + lc][s * 32 + g * 8];
                acc[nt] = __builtin_amdgcn_mfma_f32_16x16x32_bf16(qf[s], kf, acc[nt], 0, 0, 0);
            }
        #pragma unroll
        for (int nt = 0; nt < 4; ++nt)
            #pragma unroll
            for (int e = 0; e < 4; ++e) {
                float p = __expf(acc[nt][e] + c2[e]);
                attnb[(size_t)(w * 16 + 4 * g + e) * SLEN + t * KT + nt * 16 + lc] = p;
                lp[w][4 * g + e][nt * 16 + lc] = f2bf(p);
            }
        const short* lvb = lv[t & 1];
        #pragma unroll
        for (int kc = 0; kc < 2; ++kc) {
            bf16x8 pf = *(const bf16x8*)&lp[w][lc][kc * 32 + g * 8];
            #pragma unroll
            for (int nt = 0; nt < 4; ++nt) {
                int d0 = nt * 16 + lc;
                int idx = (d0 * 72 + kc * 32 + g * 8) ^ (((d0 >> 3) & 7) << 3);
                bf16x8 vfrag = *(const bf16x8*)&lvb[idx];
                oacc[nt] = __builtin_amdgcn_mfma_f32_16x16x32_bf16(pf, vfrag, oacc[nt], 0, 0, 0);
            }
        }
        if (pre) {
            #pragma unroll
            for (int q4 = 0; q4 < 4; ++q4) {
                short4 s4 = { f2bf(kr[q4].x), f2bf(kr[q4].y), f2bf(kr[q4].z), f2bf(kr[q4].w) };
                *(short4*)&lk[(t + 1) & 1][q4 * 16 + sr][sc] = s4;
                float fv[4] = { vr[q4].x, vr[q4].y, vr[q4].z, vr[q4].w };
                #pragma unroll
                for (int j = 0; j < 4; ++j) {
                    int d = sc + j;
                    int idx = (d * 72 + q4 * 16 + sr) ^ (((d >> 3) & 7) << 3);
                    lv[(t + 1) & 1][idx] = f2bf(fv[j]);
                }
            }
        }
        __syncthreads();
    }
    #pragma unroll
    for (int nt = 0; nt < 4; ++nt)
        #pragma unroll
        for (int e = 0; e < 4; ++e)
            outb[(w * 16 + 4 * g + e) * DH + nt * 16 + lc] = oacc[nt][e];
}

extern "C" void kernel_launch(void* const* d_in, const int* in_sizes, int n_in,
                              void* d_out, int out_size, void* d_ws, size_t ws_size,
                              hipStream_t stream) {
    const float* Q = (const float*)d_in[0];
    const float* K = (const float*)d_in[1];
    const float* V = (const float*)d_in[2];
    float* out  = (float*)d_out;
    float* attn = out + (size_t)NBH * SLEN * DH;   // out first, then attn (return order)

    const size_t nelem = (size_t)NBH * SLEN * DH;  // 8388608 per tensor
    if (ws_size >= 2 * nelem * sizeof(short)) {
        short* Kw = (short*)d_ws;
        short* Vt = Kw + nelem;
        hipMemsetAsync(out, 0, nelem * sizeof(float), stream);   // zero base for atomic PV
        conv_kernel<<<dim3(2048, 2), dim3(256), 0, stream>>>(K, V, Kw, Vt);
        sdpa_main<<<dim3(4096), dim3(256), 0, stream>>>(Q, Kw, Vt, out, attn);
    } else {
        sdpa_fallback<<<dim3(2048), dim3(256), 0, stream>>>(Q, K, V, out, attn);
    }
}